// Round 4
// baseline (444.109 us; speedup 1.0000x reference)
//
#include <hip/hip_runtime.h>
#include <hip/hip_fp16.h>
#include <hip/hip_cooperative_groups.h>

namespace cg = cooperative_groups;

// GCN 2-layer forward: out = softmax( A_norm @ relu(A_norm @ (x@W1) + b1) @ W2 + b2 )
// A_norm = D^-1/2 (A + I) D^-1/2, edges are col->row (row = target).
//
// R16 -> R17: ONE COOPERATIVE MEGA-KERNEL. R13-R16 per-kernel data-path
// changes each moved <=4us while honest rooflines sum to ~40us vs 162us
// measured -> the unexplained cost is between dispatches (4 full drain+
// relaunch boundaries + memset dispatch). Fuse everything into a single
// cooperative kernel with 4 grid.sync()s; memset folded into phase 0.
// Math identical to R16 (fp8 h-rows, dinv at gather, fp32 accum) => absmax
// must stay 0.00390625. Grid = 782 blocks (= bin 391 + gemm 391 = nb),
// LDS 37.1KB -> 4 blocks/CU; host clamps grid with the occupancy API and
// every phase is grid-stride so any grid size is correct.
// Phases: 0 zero relcur/zero-row | A bin||gemm | B sort | C agg1 | D agg2.

typedef _Float16 f16x8 __attribute__((ext_vector_type(8)));
typedef float f32x4 __attribute__((ext_vector_type(4)));
typedef float f32x2 __attribute__((ext_vector_type(2)));

#define CAPSH 12
#define CAP (1 << CAPSH)          // per-bucket pairbuf/scol capacity
#define NBK 784                   // LDS array size (>= nb = 782)

__device__ __forceinline__ unsigned char pack_fp8(float v) {
    return (unsigned char)(__builtin_amdgcn_cvt_pk_fp8_f32(v, 0.f, 0, false) & 0xFF);
}

__device__ __forceinline__ void unpack8_fp8(uint2 w, float* f) {
    f32x2 a = __builtin_amdgcn_cvt_pk_f32_fp8(w.x, false);
    f32x2 b = __builtin_amdgcn_cvt_pk_f32_fp8(w.x, true);
    f32x2 c = __builtin_amdgcn_cvt_pk_f32_fp8(w.y, false);
    f32x2 d = __builtin_amdgcn_cvt_pk_f32_fp8(w.y, true);
    f[0] = a.x; f[1] = a.y; f[2] = b.x; f[3] = b.y;
    f[4] = c.x; f[5] = c.y; f[6] = d.x; f[7] = d.y;
}

__global__ __launch_bounds__(256, 4) void k_mega(const int* __restrict__ row,
                                                 const int* __restrict__ col,
                                                 int* __restrict__ relcur,
                                                 unsigned* __restrict__ pairbuf,
                                                 unsigned char* __restrict__ hp8,
                                                 const float* __restrict__ x,
                                                 const float* __restrict__ W1,
                                                 int* __restrict__ scol,
                                                 int* __restrict__ offsets,
                                                 int* __restrict__ deg,
                                                 float* __restrict__ dinv,
                                                 const float* __restrict__ b1,
                                                 const float* __restrict__ W2,
                                                 float2* __restrict__ h2p,
                                                 const float* __restrict__ b2,
                                                 float2* __restrict__ out,
                                                 int E, int nb, int N, int nTileB, int SENT) {
    cg::grid_group grid = cg::this_grid();

    __shared__ unsigned items[4096];        // (r&127)<<24 | col
    __shared__ unsigned short bktid[4096];
    __shared__ int cnt[NBK];                // sort phase reuses [0..255]
    __shared__ int start0[NBK];             // sort phase: spre
    __shared__ int cursor[NBK];             // sort phase: cur
    __shared__ int gbase[NBK];

    const int tid = threadIdx.x;
    const int bid = blockIdx.x;
    const int G = gridDim.x;

    // ---------------- phase 0: zero relcur + zero row ----------------
    for (int t = bid * 256 + tid; t < nb; t += G * 256) relcur[t] = 0;
    if (bid == 0 && tid < 16) ((int*)(hp8 + (size_t)N * 64))[tid] = 0;
    grid.sync();

    // ---------------- phase A: bin (blocks < nTileB) || gemm --------
    const int nGemm = (N + 255) >> 8;
    for (int bb = bid; bb < nTileB + nGemm; bb += G) {
        if (bb < nTileB) {
            // ------------------- bin role -------------------
            int base = bb * 4096;
            int m = E - base; if (m > 4096) m = 4096;

            for (int t = tid; t < nb; t += 256) cnt[t] = 0;
            __syncthreads();
            for (int i = tid; i < m; i += 256) atomicAdd(&cnt[row[base + i] >> 7], 1);
            __syncthreads();
            // wave0: exclusive scan of tile counts (13 chunks of 64)
            if (tid < 64) {
                int lane = tid, running = 0;
                for (int ch = 0; ch < 13; ++ch) {
                    int idx = ch * 64 + lane;
                    int v = (idx < nb) ? cnt[idx] : 0;
                    int s = v;
#pragma unroll
                    for (int off = 1; off < 64; off <<= 1) {
                        int t2 = __shfl_up(s, off, 64);
                        if (lane >= off) s += t2;
                    }
                    if (idx < nb) { start0[idx] = running + s - v; cursor[idx] = running + s - v; }
                    running += __shfl(s, 63, 64);
                }
            }
            __syncthreads();
            for (int i = tid; i < m; i += 256) {
                int r = row[base + i];
                int c = col[base + i];
                int b = r >> 7;
                int pos = atomicAdd(&cursor[b], 1);
                items[pos] = ((unsigned)(r & 127) << 24) | (unsigned)c;
                bktid[pos] = (unsigned short)b;
            }
            __syncthreads();
            for (int t = tid; t < nb; t += 256) {
                int cv = cnt[t];
                if (cv > 0) gbase[t] = (t << CAPSH) + atomicAdd(&relcur[t], cv);
            }
            __syncthreads();
            for (int i = tid; i < m; i += 256) {
                int b = bktid[i];
                pairbuf[gbase[b] + (i - start0[b])] = items[i];
            }
            __syncthreads();     // protect LDS before a possible next bb iter
        } else {
            // ------------------- gemm role ------------------
            int g = bb - nTileB;
            int n0 = g << 8;                       // 256 nodes per gemm block
            int lane = tid & 63, q = lane >> 4, mm = lane & 15;
            f16x8 bf[4][2];
#pragma unroll
            for (int nt = 0; nt < 4; ++nt)
#pragma unroll
                for (int kk = 0; kk < 2; ++kk)
#pragma unroll
                    for (int j = 0; j < 8; ++j)
                        bf[nt][kk][j] = (_Float16)W1[(kk * 32 + q * 8 + j) * 64 + nt * 16 + mm];

            int nn = N - n0; if (nn > 256) nn = 256;   // N%16==0 -> whole tiles
            for (int t = (tid >> 6); t < (nn >> 4); t += 4) {
                const float* xrow = x + (size_t)(n0 + t * 16 + mm) * 64;
                float4 u0 = *(const float4*)(xrow + q * 8);
                float4 u1 = *(const float4*)(xrow + q * 8 + 4);
                float4 u2 = *(const float4*)(xrow + 32 + q * 8);
                float4 u3 = *(const float4*)(xrow + 32 + q * 8 + 4);
                f16x8 a0, a1;
                a0[0] = (_Float16)u0.x; a0[1] = (_Float16)u0.y; a0[2] = (_Float16)u0.z; a0[3] = (_Float16)u0.w;
                a0[4] = (_Float16)u1.x; a0[5] = (_Float16)u1.y; a0[6] = (_Float16)u1.z; a0[7] = (_Float16)u1.w;
                a1[0] = (_Float16)u2.x; a1[1] = (_Float16)u2.y; a1[2] = (_Float16)u2.z; a1[3] = (_Float16)u2.w;
                a1[4] = (_Float16)u3.x; a1[5] = (_Float16)u3.y; a1[6] = (_Float16)u3.z; a1[7] = (_Float16)u3.w;
                f32x4 ac0 = {0.f, 0.f, 0.f, 0.f}, ac1 = ac0, ac2 = ac0, ac3 = ac0;
                ac0 = __builtin_amdgcn_mfma_f32_16x16x32_f16(a0, bf[0][0], ac0, 0, 0, 0);
                ac1 = __builtin_amdgcn_mfma_f32_16x16x32_f16(a0, bf[1][0], ac1, 0, 0, 0);
                ac2 = __builtin_amdgcn_mfma_f32_16x16x32_f16(a0, bf[2][0], ac2, 0, 0, 0);
                ac3 = __builtin_amdgcn_mfma_f32_16x16x32_f16(a0, bf[3][0], ac3, 0, 0, 0);
                ac0 = __builtin_amdgcn_mfma_f32_16x16x32_f16(a1, bf[0][1], ac0, 0, 0, 0);
                ac1 = __builtin_amdgcn_mfma_f32_16x16x32_f16(a1, bf[1][1], ac1, 0, 0, 0);
                ac2 = __builtin_amdgcn_mfma_f32_16x16x32_f16(a1, bf[2][1], ac2, 0, 0, 0);
                ac3 = __builtin_amdgcn_mfma_f32_16x16x32_f16(a1, bf[3][1], ac3, 0, 0, 0);
#pragma unroll
                for (int reg = 0; reg < 4; ++reg) {
                    int rl = t * 16 + q * 4 + reg;
                    unsigned char* dst = hp8 + (size_t)(n0 + rl) * 64 + mm;
                    dst[0]  = pack_fp8(ac0[reg]);   // UNSCALED h, e4m3
                    dst[16] = pack_fp8(ac1[reg]);
                    dst[32] = pack_fp8(ac2[reg]);
                    dst[48] = pack_fp8(ac3[reg]);
                }
            }
        }
    }
    grid.sync();

    // ---------------- phase B: per-bucket counting sort -> CSR -------
    for (int b = bid; b < nb; b += G) {
        int lo = b << CAPSH;
        int hi = lo + relcur[b];
        cnt[tid] = 0;
        __syncthreads();
        for (int i = lo + tid; i < hi; i += 256)
            atomicAdd(&cnt[pairbuf[i] >> 24], 1);      // values in [0,128)
        __syncthreads();
        if (tid < 64) {
            int lane = tid, running = 0;
#pragma unroll
            for (int ch = 0; ch < 2; ++ch) {
                int idx = ch * 64 + lane;
                int v = cnt[idx];
                int s = v;
#pragma unroll
                for (int off = 1; off < 64; off <<= 1) {
                    int t2 = __shfl_up(s, off, 64);
                    if (lane >= off) s += t2;
                }
                start0[idx] = running + s - v;          // spre
                running += __shfl(s, 63, 64);
            }
        }
        __syncthreads();
        int n0 = b << 7;
        if (tid < 128) {
            int cv = cnt[tid];
            int excl = start0[tid];
            int n = n0 + tid;
            if (n < N) {
                offsets[n] = lo + excl;
                deg[n] = cv;
                dinv[n] = rsqrtf((float)(cv + 1));     // +1 self-loop
            }
            cursor[tid] = lo + excl;                   // cur
        }
        if (b == 0 && tid == 0) {
            offsets[N] = 0; deg[N] = 0;                // clamped-node entry
            dinv[N] = 0.f;                             // sentinel scale (never NaN)
            scol[nb << CAPSH] = N;                     // sentinel -> zero row
        }
        __syncthreads();
        for (int i = lo + tid; i < hi; i += 256) {
            unsigned it = pairbuf[i];
            int pos = atomicAdd(&cursor[it >> 24], 1);
            scol[pos] = (int)(it & 0xFFFFFFu);
        }
        __syncthreads();     // protect LDS before next bucket iteration
    }
    grid.sync();

    // ---------------- phase C: agg1 (fp8 gather, fp32 accum) ---------
    {
        int lane = tid & 63;
        int slot = lane >> 3;
        int chunk = lane & 7;
        int nwaves = (N + 7) >> 3;
        const uint2* hp2 = (const uint2*)hp8;     // row stride = 8 uint2 (64 B)
        for (int wid = (bid * 256 + tid) >> 6; wid < nwaves; wid += G * 4) {
            int n = wid * 8 + slot;
            int nc = (n < N) ? n : N;                 // row N of hp8 is the zero row
            int start = offsets[nc];
            int dg = deg[nc];                         // deg[N] = 0
            int maxd = dg;
#pragma unroll
            for (int s = 8; s <= 32; s <<= 1) {
                int o = __shfl_xor(maxd, s, 64);
                maxd = (o > maxd) ? o : maxd;
            }
            float dn = dinv[(n < N) ? n : (N - 1)];
            float af[8];
            {
                uint2 sr = hp2[(size_t)nc * 8 + chunk];   // self term (unscaled h)
                float fs[8];
                unpack8_fp8(sr, fs);
#pragma unroll
                for (int k = 0; k < 8; ++k) af[k] = dn * fs[k];
            }
            for (int j0 = 0; j0 < maxd; j0 += 8) {
                int c[8];
#pragma unroll
                for (int u = 0; u < 8; ++u)
                    c[u] = scol[(j0 + u < dg) ? (start + j0 + u) : SENT];  // SENT -> N
                uint2 r[8];
#pragma unroll
                for (int u = 0; u < 8; ++u) r[u] = hp2[(size_t)c[u] * 8 + chunk];
                float dv[8];
#pragma unroll
                for (int u = 0; u < 8; ++u) dv[u] = dinv[c[u]];            // dinv[N]=0
#pragma unroll
                for (int u = 0; u < 8; ++u) {
                    float f[8];
                    unpack8_fp8(r[u], f);
#pragma unroll
                    for (int k = 0; k < 8; ++k)
                        af[k] = fmaf(dv[u], f[k], af[k]);
                }
            }
            float4 b1a = ((const float4*)b1)[chunk * 2];
            float4 b1b = ((const float4*)b1)[chunk * 2 + 1];
            float h1[8];
            h1[0] = fmaxf(fmaf(dn, af[0], b1a.x), 0.f);
            h1[1] = fmaxf(fmaf(dn, af[1], b1a.y), 0.f);
            h1[2] = fmaxf(fmaf(dn, af[2], b1a.z), 0.f);
            h1[3] = fmaxf(fmaf(dn, af[3], b1a.w), 0.f);
            h1[4] = fmaxf(fmaf(dn, af[4], b1b.x), 0.f);
            h1[5] = fmaxf(fmaf(dn, af[5], b1b.y), 0.f);
            h1[6] = fmaxf(fmaf(dn, af[6], b1b.z), 0.f);
            h1[7] = fmaxf(fmaf(dn, af[7], b1b.w), 0.f);
            float p0 = 0.f, p1 = 0.f;
#pragma unroll
            for (int k = 0; k < 4; ++k) {   // float4 = W2 rows {8c+2k, 8c+2k+1}
                float4 w = ((const float4*)W2)[chunk * 4 + k];
                p0 = fmaf(h1[2 * k], w.x, p0); p1 = fmaf(h1[2 * k], w.y, p1);
                p0 = fmaf(h1[2 * k + 1], w.z, p0); p1 = fmaf(h1[2 * k + 1], w.w, p1);
            }
#pragma unroll
            for (int s = 1; s <= 4; s <<= 1) {  // reduce across chunk (bits 0,1,2)
                p0 += __shfl_xor(p0, s, 64);
                p1 += __shfl_xor(p1, s, 64);
            }
            if (chunk == 0 && n < N) h2p[n] = make_float2(dn * p0, dn * p1);  // pre-scaled
        }
    }
    grid.sync();

    // ---------------- phase D: agg2 + softmax (16 lanes/node) --------
    {
        float bb0 = b2[0], bb1 = b2[1];
        for (int gtid = bid * 256 + tid; gtid < N * 16; gtid += G * 256) {
            int n = gtid >> 4;
            int sub = gtid & 15;
            int start = offsets[n], end = start + deg[n];
            float ax = 0.f, ay = 0.f;
            if (sub == 0) { float2 s = h2p[n]; ax = s.x; ay = s.y; }   // self (pre-scaled)
            for (int j = start + sub; j < end; j += 16) {
                float2 v = h2p[scol[j]];
                ax += v.x; ay += v.y;
            }
#pragma unroll
            for (int s = 1; s <= 8; s <<= 1) {
                ax += __shfl_xor(ax, s, 64);
                ay += __shfl_xor(ay, s, 64);
            }
            if (sub == 0) {
                float dn = dinv[n];
                float l0 = fmaf(dn, ax, bb0), l1 = fmaf(dn, ay, bb1);
                float m = fmaxf(l0, l1);
                float e0 = __expf(l0 - m), e1 = __expf(l1 - m);
                float inv = 1.0f / (e0 + e1);
                out[n] = make_float2(e0 * inv, e1 * inv);
            }
        }
    }
}

extern "C" void kernel_launch(void* const* d_in, const int* in_sizes, int n_in,
                              void* d_out, int out_size, void* d_ws, size_t ws_size,
                              hipStream_t stream) {
    const float* x  = (const float*)d_in[0];
    const int*   ei = (const int*)d_in[1];
    const float* W1 = (const float*)d_in[2];
    const float* b1 = (const float*)d_in[3];
    const float* W2 = (const float*)d_in[4];
    const float* b2 = (const float*)d_in[5];
    float2* out = (float2*)d_out;

    const int N = in_sizes[0] / 64;     // 100000 (N%16==0, N<2^24)
    const int E = in_sizes[1] / 2;      // 1600000
    const int nb = (N + 127) >> 7;      // 782 buckets of 128 nodes
    const int SENT = nb << CAPSH;
    const int* row = ei;
    const int* col = ei + E;

    char* p = (char*)d_ws;
    auto alloc = [&](size_t bytes) -> void* {
        void* r = (void*)p;
        p += (bytes + 255) & ~(size_t)255;
        return r;
    };
    int*   relcur  = (int*)alloc((size_t)nb * 4);
    int*   offsets = (int*)alloc((size_t)(N + 1) * 4);
    int*   deg     = (int*)alloc((size_t)(N + 1) * 4);
    float* dinv    = (float*)alloc((size_t)(N + 1) * 4);        // +1: dinv[N]=0 sentinel
    unsigned* pairbuf = (unsigned*)alloc((size_t)nb * CAP * 4);
    int*   scol    = (int*)alloc(((size_t)nb * CAP + 1) * 4);   // +1 sentinel
    unsigned char* hp8 = (unsigned char*)alloc((size_t)(N + 1) * 64);  // fp8 rows, +1 zero row
    float2* h2p    = (float2*)alloc((size_t)N * 8);

    const int nTileB = (E + 4095) / 4096;   // 391 bin blocks
    const int nGemm  = (N + 255) >> 8;      // 391 gemm blocks
    int target = nTileB + nGemm;            // 782
    if (nb > target) target = nb;

    // Clamp grid to guaranteed co-residency (cooperative launch requirement).
    static int capBlocks = 0;
    if (capBlocks == 0) {
        int maxB = 0;
        hipError_t e = hipOccupancyMaxActiveBlocksPerMultiprocessor(&maxB, (const void*)k_mega, 256, 0);
        if (e != hipSuccess || maxB < 1) maxB = 2;   // conservative fallback
        hipDeviceProp_t prop;
        int dev = 0;
        hipGetDevice(&dev);
        if (hipGetDeviceProperties(&prop, dev) != hipSuccess) prop.multiProcessorCount = 256;
        capBlocks = maxB * prop.multiProcessorCount;
        if (capBlocks < 1) capBlocks = 256;
    }
    int G = (target < capBlocks) ? target : capBlocks;

    int E_ = E, nb_ = nb, N_ = N, nTileB_ = nTileB, SENT_ = SENT;
    void* args[] = { (void*)&row, (void*)&col, (void*)&relcur, (void*)&pairbuf, (void*)&hp8,
                     (void*)&x, (void*)&W1, (void*)&scol, (void*)&offsets, (void*)&deg,
                     (void*)&dinv, (void*)&b1, (void*)&W2, (void*)&h2p, (void*)&b2,
                     (void*)&out, (void*)&E_, (void*)&nb_, (void*)&N_, (void*)&nTileB_, (void*)&SENT_ };
    hipLaunchCooperativeKernel((const void*)k_mega, dim3(G), dim3(256), args, 0, stream);
}

// Round 5
// 163.771 us; speedup vs baseline: 2.7118x; 2.7118x over previous
//
#include <hip/hip_runtime.h>
#include <hip/hip_fp16.h>

// GCN 2-layer forward: out = softmax( A_norm @ relu(A_norm @ (x@W1) + b1) @ W2 + b2 )
// A_norm = D^-1/2 (A + I) D^-1/2, edges are col->row (row = target).
//
// R17 -> R18: back to the split structure (mega-kernel regressed 2.9x with
// VALUBusy 3.6% => all phases latency-bound, parallelism-scalable; boundaries
// exonerated). This round removes WASTED latency-bound requests:
//  - agg1: waves run to max-degree of their 8 nodes (~50% sentinel slots at
//    Poisson-16 degrees). k_sort now emits a bucket-local DEGREE-SORTED node
//    order (ord); agg1 walks ord so co-waved nodes have equal degree.
//    Per-node accumulation order unchanged => h2p bitwise identical.
//  - agg2: 2-class softmax = logistic(l0-l1) => store only dn*(p0-p1) as a
//    single float h2pd (halves agg2 random-gather bytes) + 2-deep unroll.
// 5 dispatches: memset(relcur) -> bin+gemm -> sort(+ord) -> agg1 -> agg2.

typedef _Float16 f16x8 __attribute__((ext_vector_type(8)));
typedef float f32x4 __attribute__((ext_vector_type(4)));
typedef float f32x2 __attribute__((ext_vector_type(2)));

#define CAPSH 12
#define CAP (1 << CAPSH)          // per-bucket pairbuf/scol capacity
#define NBK 784                   // LDS array size (>= nb = 782)

__device__ __forceinline__ unsigned char pack_fp8(float v) {
    return (unsigned char)(__builtin_amdgcn_cvt_pk_fp8_f32(v, 0.f, 0, false) & 0xFF);
}

__device__ __forceinline__ void unpack8_fp8(uint2 w, float* f) {
    f32x2 a = __builtin_amdgcn_cvt_pk_f32_fp8(w.x, false);
    f32x2 b = __builtin_amdgcn_cvt_pk_f32_fp8(w.x, true);
    f32x2 c = __builtin_amdgcn_cvt_pk_f32_fp8(w.y, false);
    f32x2 d = __builtin_amdgcn_cvt_pk_f32_fp8(w.y, true);
    f[0] = a.x; f[1] = a.y; f[2] = b.x; f[3] = b.y;
    f[4] = c.x; f[5] = c.y; f[6] = d.x; f[7] = d.y;
}

// ---- 1. fused: bin edges into per-bucket slices  |  gemm hp8 = fp8(x@W1) ---
__global__ __launch_bounds__(256, 4) void k_binfused(const int* __restrict__ row,
                                                     const int* __restrict__ col,
                                                     int* __restrict__ relcur,
                                                     unsigned* __restrict__ pairbuf,
                                                     unsigned char* __restrict__ hp8,
                                                     const float* __restrict__ x,
                                                     const float* __restrict__ W1,
                                                     int E, int nb, int N, int nTileB) {
    __shared__ unsigned items[4096];        // (r&127)<<24 | col
    __shared__ unsigned short bktid[4096];
    __shared__ int cnt[NBK];
    __shared__ int start0[NBK];
    __shared__ int cursor[NBK];
    __shared__ int gbase[NBK];

    int tid = threadIdx.x;

    if (blockIdx.x < nTileB) {
        // ------------------------- bin role -------------------------
        int base = blockIdx.x * 4096;
        int m = E - base; if (m > 4096) m = 4096;

        for (int t = tid; t < nb; t += 256) cnt[t] = 0;
        __syncthreads();
        for (int i = tid; i < m; i += 256) atomicAdd(&cnt[row[base + i] >> 7], 1);
        __syncthreads();
        // wave0: exclusive scan of tile counts -> start0, cursor (13 chunks of 64)
        if (tid < 64) {
            int lane = tid, running = 0;
            for (int ch = 0; ch < 13; ++ch) {
                int idx = ch * 64 + lane;
                int v = (idx < nb) ? cnt[idx] : 0;
                int s = v;
#pragma unroll
                for (int off = 1; off < 64; off <<= 1) {
                    int t2 = __shfl_up(s, off, 64);
                    if (lane >= off) s += t2;
                }
                if (idx < nb) { start0[idx] = running + s - v; cursor[idx] = running + s - v; }
                running += __shfl(s, 63, 64);
            }
        }
        __syncthreads();
        for (int i = tid; i < m; i += 256) {
            int r = row[base + i];
            int c = col[base + i];
            int b = r >> 7;
            int pos = atomicAdd(&cursor[b], 1);
            items[pos] = ((unsigned)(r & 127) << 24) | (unsigned)c;
            bktid[pos] = (unsigned short)b;
        }
        __syncthreads();
        // claim global space: bucket b's slice starts at b*CAP
        for (int t = tid; t < nb; t += 256) {
            int cv = cnt[t];
            if (cv > 0) gbase[t] = (t << CAPSH) + atomicAdd(&relcur[t], cv);
        }
        __syncthreads();
        for (int i = tid; i < m; i += 256) {
            int b = bktid[i];
            pairbuf[gbase[b] + (i - start0[b])] = items[i];
        }
        if (blockIdx.x == 0 && tid < 16) ((int*)(hp8 + (size_t)N * 64))[tid] = 0;  // zero row (64B)
    } else {
        // ------------------------- gemm role ------------------------
        int g = blockIdx.x - nTileB;
        int n0 = g << 8;                       // 256 nodes per gemm block
        int lane = tid & 63, q = lane >> 4, mm = lane & 15;
        // B-frags (W1 fp16): B[k][n], n=nt*16+mm, k=kk*32+q*8+j
        f16x8 bf[4][2];
#pragma unroll
        for (int nt = 0; nt < 4; ++nt)
#pragma unroll
            for (int kk = 0; kk < 2; ++kk)
#pragma unroll
                for (int j = 0; j < 8; ++j)
                    bf[nt][kk][j] = (_Float16)W1[(kk * 32 + q * 8 + j) * 64 + nt * 16 + mm];

        int nn = N - n0; if (nn > 256) nn = 256;   // N%16==0 -> whole tiles
        for (int t = (tid >> 6); t < (nn >> 4); t += 4) {
            const float* xrow = x + (size_t)(n0 + t * 16 + mm) * 64;
            float4 u0 = *(const float4*)(xrow + q * 8);
            float4 u1 = *(const float4*)(xrow + q * 8 + 4);
            float4 u2 = *(const float4*)(xrow + 32 + q * 8);
            float4 u3 = *(const float4*)(xrow + 32 + q * 8 + 4);
            f16x8 a0, a1;
            a0[0] = (_Float16)u0.x; a0[1] = (_Float16)u0.y; a0[2] = (_Float16)u0.z; a0[3] = (_Float16)u0.w;
            a0[4] = (_Float16)u1.x; a0[5] = (_Float16)u1.y; a0[6] = (_Float16)u1.z; a0[7] = (_Float16)u1.w;
            a1[0] = (_Float16)u2.x; a1[1] = (_Float16)u2.y; a1[2] = (_Float16)u2.z; a1[3] = (_Float16)u2.w;
            a1[4] = (_Float16)u3.x; a1[5] = (_Float16)u3.y; a1[6] = (_Float16)u3.z; a1[7] = (_Float16)u3.w;
            f32x4 ac0 = {0.f, 0.f, 0.f, 0.f}, ac1 = ac0, ac2 = ac0, ac3 = ac0;
            ac0 = __builtin_amdgcn_mfma_f32_16x16x32_f16(a0, bf[0][0], ac0, 0, 0, 0);
            ac1 = __builtin_amdgcn_mfma_f32_16x16x32_f16(a0, bf[1][0], ac1, 0, 0, 0);
            ac2 = __builtin_amdgcn_mfma_f32_16x16x32_f16(a0, bf[2][0], ac2, 0, 0, 0);
            ac3 = __builtin_amdgcn_mfma_f32_16x16x32_f16(a0, bf[3][0], ac3, 0, 0, 0);
            ac0 = __builtin_amdgcn_mfma_f32_16x16x32_f16(a1, bf[0][1], ac0, 0, 0, 0);
            ac1 = __builtin_amdgcn_mfma_f32_16x16x32_f16(a1, bf[1][1], ac1, 0, 0, 0);
            ac2 = __builtin_amdgcn_mfma_f32_16x16x32_f16(a1, bf[2][1], ac2, 0, 0, 0);
            ac3 = __builtin_amdgcn_mfma_f32_16x16x32_f16(a1, bf[3][1], ac3, 0, 0, 0);
#pragma unroll
            for (int reg = 0; reg < 4; ++reg) {
                int rl = t * 16 + q * 4 + reg;
                unsigned char* dst = hp8 + (size_t)(n0 + rl) * 64 + mm;
                dst[0]  = pack_fp8(ac0[reg]);   // UNSCALED h, e4m3
                dst[16] = pack_fp8(ac1[reg]);
                dst[32] = pack_fp8(ac2[reg]);
                dst[48] = pack_fp8(ac3[reg]);
            }
        }
    }
}

// ---- 2. per-bucket counting sort -> CSR + degree-sorted node order ---------
// One block per bucket (128 nodes). Wave0 shuffle scans (1 barrier each).
__global__ __launch_bounds__(256, 4) void k_sort(const unsigned* __restrict__ pairbuf,
                                                 const int* __restrict__ relcur,
                                                 int* __restrict__ scol,
                                                 int* __restrict__ offsets,
                                                 int* __restrict__ deg,
                                                 float* __restrict__ dinv,
                                                 int* __restrict__ ord,
                                                 int N, int nb) {
    __shared__ int cnt[256];      // [128..255] stay 0
    __shared__ int spre[128];     // exclusive prefix / deg-hist
    __shared__ int cur[128];      // scatter cursors / deg-hist cursors
    int b = blockIdx.x;
    int tid = threadIdx.x;
    int lo = b << CAPSH;
    int hi = lo + relcur[b];
    cnt[tid] = 0;
    __syncthreads();
    for (int i = lo + tid; i < hi; i += 256)
        atomicAdd(&cnt[pairbuf[i] >> 24], 1);      // values in [0,128)
    __syncthreads();
    // wave0: exclusive scan of 128 counts (2 chunks of 64)
    if (tid < 64) {
        int lane = tid, running = 0;
#pragma unroll
        for (int ch = 0; ch < 2; ++ch) {
            int idx = ch * 64 + lane;
            int v = cnt[idx];
            int s = v;
#pragma unroll
            for (int off = 1; off < 64; off <<= 1) {
                int t2 = __shfl_up(s, off, 64);
                if (lane >= off) s += t2;
            }
            spre[idx] = running + s - v;
            running += __shfl(s, 63, 64);
        }
    }
    __syncthreads();
    int n0 = b << 7;
    if (tid < 128) {
        int cv = cnt[tid];
        int excl = spre[tid];
        int n = n0 + tid;
        if (n < N) {
            offsets[n] = lo + excl;
            deg[n] = cv;
            dinv[n] = rsqrtf((float)(cv + 1));     // +1 self-loop
        }
        cur[tid] = lo + excl;
    }
    if (b == 0 && tid == 0) {
        offsets[N] = 0; deg[N] = 0;                // clamped-node entry
        dinv[N] = 0.f;                             // sentinel scale -> 0 (never NaN)
        scol[nb << CAPSH] = N;                     // sentinel -> zero row
    }
    __syncthreads();
    for (int i = lo + tid; i < hi; i += 256) {
        unsigned it = pairbuf[i];
        int pos = atomicAdd(&cur[it >> 24], 1);
        scol[pos] = (int)(it & 0xFFFFFFu);
    }
    // ---- degree-sorted node order for this bucket (counting sort, 128 bins)
    // Tail nodes (n >= N) have cnt==0 (rows < N only) -> land at front, and
    // agg1 guards on n < N.
    __syncthreads();
    if (tid < 128) spre[tid] = 0;                  // reuse spre as deg-hist
    __syncthreads();
    int binv = 0;
    if (tid < 128) {
        binv = cnt[tid]; if (binv > 127) binv = 127;
        atomicAdd(&spre[binv], 1);
    }
    __syncthreads();
    if (tid < 64) {                                // scan hist -> cur (exclusive)
        int lane = tid, running = 0;
#pragma unroll
        for (int ch = 0; ch < 2; ++ch) {
            int idx = ch * 64 + lane;
            int v = spre[idx];
            int s = v;
#pragma unroll
            for (int off = 1; off < 64; off <<= 1) {
                int t2 = __shfl_up(s, off, 64);
                if (lane >= off) s += t2;
            }
            cur[idx] = running + s - v;
            running += __shfl(s, 63, 64);
        }
    }
    __syncthreads();
    if (tid < 128) {
        int pos = atomicAdd(&cur[binv], 1);
        ord[(b << 7) + pos] = n0 + tid;            // may be >= N for tail bucket
    }
}

// ---- 3. layer-1 agg (fp8 gather, dinv at gather, fp32 accum) + b1/relu/W2 --
// Wave = 8 DEGREE-MATCHED nodes via ord; slot=lane>>3, chunk=lane&7 (8B each).
__global__ __launch_bounds__(256, 4) void k_agg1(const unsigned char* __restrict__ hp8,
                                                 const int* __restrict__ offsets,
                                                 const int* __restrict__ deg,
                                                 const int* __restrict__ scol,
                                                 const float* __restrict__ dinv,
                                                 const int* __restrict__ ord,
                                                 const float* __restrict__ b1,
                                                 const float* __restrict__ W2,
                                                 float* __restrict__ h2pd,
                                                 int N, int SENT, int nwaves) {
    int lane = threadIdx.x & 63;
    int slot = lane >> 3;
    int chunk = lane & 7;
    int wid = (int)((blockIdx.x * 256 + threadIdx.x) >> 6);
    if (blockIdx.x == 0 && threadIdx.x == 0) h2pd[N] = 0.f;   // sentinel for agg2
    if (wid >= nwaves) return;
    int n = ord[wid * 8 + slot];              // degree-sorted id (may be >= N)
    int nc = (n < N) ? n : N;                 // row N of hp8 is the zero row
    int start = offsets[nc];
    int dg = deg[nc];                         // deg[N] = 0
    int maxd = dg;
#pragma unroll
    for (int s = 8; s <= 32; s <<= 1) {
        int o = __shfl_xor(maxd, s, 64);
        maxd = (o > maxd) ? o : maxd;
    }
    const uint2* hp2 = (const uint2*)hp8;     // row stride = 8 uint2 (64 B)
    float dn = dinv[nc];                      // dinv[N] = 0
    float af[8];
    {
        uint2 sr = hp2[(size_t)nc * 8 + chunk];   // self term (unscaled h)
        float fs[8];
        unpack8_fp8(sr, fs);
#pragma unroll
        for (int k = 0; k < 8; ++k) af[k] = dn * fs[k];
    }
    for (int j0 = 0; j0 < maxd; j0 += 8) {
        int c[8];
#pragma unroll
        for (int u = 0; u < 8; ++u)
            c[u] = scol[(j0 + u < dg) ? (start + j0 + u) : SENT];  // SENT -> N
        uint2 r[8];
#pragma unroll
        for (int u = 0; u < 8; ++u) r[u] = hp2[(size_t)c[u] * 8 + chunk];
        float dv[8];
#pragma unroll
        for (int u = 0; u < 8; ++u) dv[u] = dinv[c[u]];            // dinv[N]=0
#pragma unroll
        for (int u = 0; u < 8; ++u) {
            float f[8];
            unpack8_fp8(r[u], f);
#pragma unroll
            for (int k = 0; k < 8; ++k)
                af[k] = fmaf(dv[u], f[k], af[k]);
        }
    }
    float4 b1a = ((const float4*)b1)[chunk * 2];
    float4 b1b = ((const float4*)b1)[chunk * 2 + 1];
    float h1[8];
    h1[0] = fmaxf(fmaf(dn, af[0], b1a.x), 0.f);
    h1[1] = fmaxf(fmaf(dn, af[1], b1a.y), 0.f);
    h1[2] = fmaxf(fmaf(dn, af[2], b1a.z), 0.f);
    h1[3] = fmaxf(fmaf(dn, af[3], b1a.w), 0.f);
    h1[4] = fmaxf(fmaf(dn, af[4], b1b.x), 0.f);
    h1[5] = fmaxf(fmaf(dn, af[5], b1b.y), 0.f);
    h1[6] = fmaxf(fmaf(dn, af[6], b1b.z), 0.f);
    h1[7] = fmaxf(fmaf(dn, af[7], b1b.w), 0.f);
    float p0 = 0.f, p1 = 0.f;
#pragma unroll
    for (int k = 0; k < 4; ++k) {   // float4 = W2 rows {8c+2k, 8c+2k+1}
        float4 w = ((const float4*)W2)[chunk * 4 + k];
        p0 = fmaf(h1[2 * k], w.x, p0); p1 = fmaf(h1[2 * k], w.y, p1);
        p0 = fmaf(h1[2 * k + 1], w.z, p0); p1 = fmaf(h1[2 * k + 1], w.w, p1);
    }
#pragma unroll
    for (int s = 1; s <= 4; s <<= 1) {  // reduce across chunk (bits 0,1,2)
        p0 += __shfl_xor(p0, s, 64);
        p1 += __shfl_xor(p1, s, 64);
    }
    if (chunk == 0 && n < N) h2pd[n] = dn * (p0 - p1);   // pre-scaled logit DELTA
}

// ---- 4. layer-2 agg + 2-class softmax = logistic(delta); 16 lanes/node -----
__global__ __launch_bounds__(256) void k_agg2(const float* __restrict__ h2pd,
                                              const int* __restrict__ offsets,
                                              const int* __restrict__ deg,
                                              const int* __restrict__ scol,
                                              const float* __restrict__ dinv,
                                              const float* __restrict__ b2,
                                              float2* __restrict__ out, int N, int SENT) {
    int gtid = blockIdx.x * 256 + threadIdx.x;
    int n = gtid >> 4;
    int sub = threadIdx.x & 15;
    if (n >= N) return;
    int start = offsets[n], end = start + deg[n];
    float ax = 0.f, ay = 0.f;                 // two independent chains (ILP)
    if (sub == 0) ax = h2pd[n];               // self (pre-scaled)
    for (int j = start + sub; j < end; j += 32) {
        int c0 = scol[j];
        int c1 = (j + 16 < end) ? scol[j + 16] : SENT;  // scol[SENT]=N, h2pd[N]=0
        ax += h2pd[c0];
        ay += h2pd[c1];
    }
    ax += ay;
#pragma unroll
    for (int s = 1; s <= 8; s <<= 1)
        ax += __shfl_xor(ax, s, 64);
    if (sub == 0) {
        float dn = dinv[n];
        float ld = fmaf(dn, ax, b2[0] - b2[1]);   // l0 - l1
        float e = __expf(-ld);                     // = exp(l1 - l0)
        float inv = 1.0f / (1.0f + e);
        out[n] = make_float2(inv, e * inv);
    }
}

extern "C" void kernel_launch(void* const* d_in, const int* in_sizes, int n_in,
                              void* d_out, int out_size, void* d_ws, size_t ws_size,
                              hipStream_t stream) {
    const float* x  = (const float*)d_in[0];
    const int*   ei = (const int*)d_in[1];
    const float* W1 = (const float*)d_in[2];
    const float* b1 = (const float*)d_in[3];
    const float* W2 = (const float*)d_in[4];
    const float* b2 = (const float*)d_in[5];
    float2* out = (float2*)d_out;

    const int N = in_sizes[0] / 64;     // 100000 (N%16==0, N<2^24)
    const int E = in_sizes[1] / 2;      // 1600000
    const int nb = (N + 127) >> 7;      // 782 buckets of 128 nodes
    const int SENT = nb << CAPSH;
    const int* row = ei;
    const int* col = ei + E;

    char* p = (char*)d_ws;
    auto alloc = [&](size_t bytes) -> void* {
        void* r = (void*)p;
        p += (bytes + 255) & ~(size_t)255;
        return r;
    };
    int*   relcur  = (int*)alloc((size_t)nb * 4);               // memset exact (R4 lesson)
    int*   offsets = (int*)alloc((size_t)(N + 1) * 4);
    int*   deg     = (int*)alloc((size_t)(N + 1) * 4);
    float* dinv    = (float*)alloc((size_t)(N + 1) * 4);        // +1: dinv[N]=0 sentinel
    unsigned* pairbuf = (unsigned*)alloc((size_t)nb * CAP * 4);
    int*   scol    = (int*)alloc(((size_t)nb * CAP + 1) * 4);   // +1 sentinel
    unsigned char* hp8 = (unsigned char*)alloc((size_t)(N + 1) * 64);  // fp8 rows, +1 zero row
    float* h2pd    = (float*)alloc((size_t)(N + 1) * 4);        // logit delta, +1 sentinel
    int*   ord     = (int*)alloc((size_t)nb * 128 * 4);         // degree-sorted ids

    const int nTileB = (E + 4095) / 4096;   // 391 bin blocks
    const int nGemm  = (N + 255) >> 8;      // 391 gemm blocks (256 nodes each)

    hipMemsetAsync(relcur, 0, (size_t)nb * 4, stream);
    k_binfused<<<nTileB + nGemm, 256, 0, stream>>>(row, col, relcur, pairbuf, hp8,
                                                   x, W1, E, nb, N, nTileB);
    k_sort<<<nb, 256, 0, stream>>>(pairbuf, relcur, scol, offsets, deg, dinv, ord, N, nb);
    const int nwaves = nb * 16;                      // 8 ord-nodes per wave
    k_agg1<<<nb * 4, 256, 0, stream>>>(hp8, offsets, deg, scol, dinv, ord, b1, W2, h2pd, N, SENT, nwaves);
    k_agg2<<<(N * 16 + 255) / 256, 256, 0, stream>>>(h2pd, offsets, deg, scol, dinv, b2, out, N, SENT);
}